// Round 2
// baseline (629.133 us; speedup 1.0000x reference)
//
#include <hip/hip_runtime.h>

typedef __bf16 bf16;
typedef __bf16 bf16x8 __attribute__((ext_vector_type(8)));
typedef float f32x4 __attribute__((ext_vector_type(4)));
typedef _Float16 f16x8 __attribute__((ext_vector_type(8)));

// ---------------- workspace layout (bytes) ----------------
// S   fp16 [4096][8192]  67,108,864   @ 0          (reused for H bf16 [4096][4096] later)
// CW  bf16 [4096][8192]  67,108,864   @ 67,108,864
// MT  bf16 [1024][8192]  16,777,216   @ 134,217,728
// W1B bf16 [4096][2048]  16,777,216   @ 150,994,944
// W2B bf16 [1024][4096]   8,388,608   @ 167,772,160  (rows 1000..1023 zero-padded)
// FI  bf16 [4096][2048]  16,777,216   @ 176,160,768  (cols 0..1023 enc, 1024..2047 memvec)
// XN  bf16 [4096][1024]   8,388,608   @ 192,937,984
// YN  bf16 [8192][1024]  16,777,216   @ 201,326,592
// total 218,103,808
#define WS_OFF_S    (0ull)
#define WS_OFF_CW   (67108864ull)
#define WS_OFF_MT   (134217728ull)
#define WS_OFF_W1B  (150994944ull)
#define WS_OFF_W2B  (167772160ull)
#define WS_OFF_FI   (176160768ull)
#define WS_OFF_XN   (192937984ull)
#define WS_OFF_YN   (201326592ull)
#define WS_OFF_H    (0ull)

__device__ __forceinline__ void gload_lds16(const void* g, void* l) {
  __builtin_amdgcn_global_load_lds(
      (const __attribute__((address_space(1))) void*)g,
      (__attribute__((address_space(3))) void*)l, 16, 0, 0);
}

// ---------------- NT bf16 GEMM: C = A[M,K] * B[N,K]^T ----------------
// 128x128 tile, BK=64, 256 threads (4 waves 2x2), mfma_f32_16x16x32_bf16.
// Staging: per wave, 4 x global_load_lds dwordx4 per tile-half (each issue =
// 64 lanes x 16 B = 1024 B = 8 rows). Linear LDS dest; global source col is
// inverse-swizzled (byte ^= ((row&7)<<4)); ds_read_b128 applies the same XOR
// -> 2-way bank conflict (free).  LDS[row][c] = G[row][c ^ ((row&7)<<4)].
// EPI: 0 = fp16 store (scores) | 1 = bf16 store at col offset (concat buffer)
//      2 = +bias, ReLU, bf16    | 3 = +bias, fp32, col<colLimit predicate
template<int EPI>
__global__ __launch_bounds__(256)
void gemm_nt(const bf16* __restrict__ A, const bf16* __restrict__ B,
             void* __restrict__ Cout, const float* __restrict__ bias,
             int K, int ldc, int colLimit, int colOffset)
{
  __shared__ alignas(16) bf16 As[128 * 64];
  __shared__ alignas(16) bf16 Bs[128 * 64];
  const int tid  = threadIdx.x;
  const int lane = tid & 63;
  const int wave = tid >> 6;
  const int wr = wave >> 1, wc = wave & 1;
  const int bm0 = blockIdx.y << 7;
  const int bn0 = blockIdx.x << 7;

  // staging: wave w owns tile rows [32w, 32w+32) = LDS bytes [w*4096, (w+1)*4096)
  // issue i covers rows 32w+8i .. 32w+8i+7 (1024 B)
  const int lr   = lane >> 3;                    // 0..7: row within 8-row group
  const int lcb  = (lane & 7) << 4;              // byte col 0..112
  const int scolb = lcb ^ (lr << 4);             // inverse-swizzled source col (row&7==lr)
  const int row0 = (wave << 5) + lr;
  const char* Ag = (const char*)(A + (size_t)(bm0 + row0) * K) + scolb;
  const char* Bg = (const char*)(B + (size_t)(bn0 + row0) * K) + scolb;
  char* Al = (char*)As + (wave << 12);
  char* Bl = (char*)Bs + (wave << 12);
  const size_t rstride8 = (size_t)16 * K;        // 8 rows * K * 2 bytes

  // precomputed swizzled ds_read byte offsets (constant across K loop)
  int offA[2][4], offB[2][4];
  const int kb = (lane >> 4) << 4;               // lane's 16B k-slot
#pragma unroll
  for (int m = 0; m < 4; ++m) {
    const int rA = (wr << 6) + (m << 4) + (lane & 15);
    const int rB = (wc << 6) + (m << 4) + (lane & 15);
#pragma unroll
    for (int ks = 0; ks < 2; ++ks) {
      offA[ks][m] = (rA << 7) + ((((ks << 6) + kb)) ^ ((rA & 7) << 4));
      offB[ks][m] = (rB << 7) + ((((ks << 6) + kb)) ^ ((rB & 7) << 4));
    }
  }

  f32x4 acc[4][4];
#pragma unroll
  for (int m = 0; m < 4; ++m)
#pragma unroll
    for (int n = 0; n < 4; ++n) acc[m][n] = (f32x4)(0.0f);

  const char* Asb = (const char*)As;
  const char* Bsb = (const char*)Bs;
  const int nk = K >> 6;
  for (int kt = 0; kt < nk; ++kt) {
#pragma unroll
    for (int i = 0; i < 4; ++i) gload_lds16(Ag + i * rstride8, Al + (i << 10));
#pragma unroll
    for (int i = 0; i < 4; ++i) gload_lds16(Bg + i * rstride8, Bl + (i << 10));
    Ag += 128; Bg += 128;                        // BK*2 bytes
    __syncthreads();                             // drains vmcnt -> LDS ready
#pragma unroll
    for (int ks = 0; ks < 2; ++ks) {
      bf16x8 av[4], bv[4];
#pragma unroll
      for (int m = 0; m < 4; ++m) av[m] = *(const bf16x8*)(Asb + offA[ks][m]);
#pragma unroll
      for (int n = 0; n < 4; ++n) bv[n] = *(const bf16x8*)(Bsb + offB[ks][n]);
#pragma unroll
      for (int m = 0; m < 4; ++m)
#pragma unroll
        for (int n = 0; n < 4; ++n)
          acc[m][n] = __builtin_amdgcn_mfma_f32_16x16x32_bf16(av[m], bv[n], acc[m][n], 0, 0, 0);
    }
    __syncthreads();                             // before next stage overwrites
  }

  // epilogue: C/D layout col = lane&15, row = (lane>>4)*4 + j  [m89/m91 verified]
  const int r0 = bm0 + (wr << 6) + ((lane >> 4) << 2);
  const int c0 = bn0 + (wc << 6) + (lane & 15);
#pragma unroll
  for (int m = 0; m < 4; ++m) {
#pragma unroll
    for (int n = 0; n < 4; ++n) {
      const int col = c0 + (n << 4);
#pragma unroll
      for (int j = 0; j < 4; ++j) {
        const int row = r0 + (m << 4) + j;
        const float v = acc[m][n][j];
        if (EPI == 0) {
          ((_Float16*)Cout)[(size_t)row * ldc + col] = (_Float16)v;
        } else if (EPI == 1) {
          ((bf16*)Cout)[(size_t)row * ldc + colOffset + col] = (bf16)v;
        } else if (EPI == 2) {
          float t = v + bias[col];
          t = t > 0.f ? t : 0.f;
          ((bf16*)Cout)[(size_t)row * ldc + col] = (bf16)t;
        } else {
          if (col < colLimit)
            ((float*)Cout)[(size_t)row * ldc + col] = v + bias[col];
        }
      }
    }
  }
}

// ---------------- row-normalize fp32 -> bf16 (and optional raw bf16 copy) ----------------
// one block per row, dim=1024 fixed, 256 threads * float4
__global__ __launch_bounds__(256)
void rownorm_kernel(const float* __restrict__ X, bf16* __restrict__ XN,
                    bf16* __restrict__ RAW, int ldraw)
{
  const int row = blockIdx.x;
  const int tid = threadIdx.x;
  const float4 v = ((const float4*)(X + (size_t)row * 1024))[tid];
  float ss = v.x * v.x + v.y * v.y + v.z * v.z + v.w * v.w;
#pragma unroll
  for (int o = 32; o > 0; o >>= 1) ss += __shfl_down(ss, o);
  __shared__ float red[4];
  if ((tid & 63) == 0) red[tid >> 6] = ss;
  __syncthreads();
  const float rn = rsqrtf(red[0] + red[1] + red[2] + red[3] + 1e-6f);
  union { bf16 h[4]; unsigned long long u; } p;
  p.h[0] = (bf16)(v.x * rn); p.h[1] = (bf16)(v.y * rn);
  p.h[2] = (bf16)(v.z * rn); p.h[3] = (bf16)(v.w * rn);
  ((unsigned long long*)(XN + (size_t)row * 1024))[tid] = p.u;
  if (RAW != nullptr) {
    union { bf16 h[4]; unsigned long long u; } q;
    q.h[0] = (bf16)v.x; q.h[1] = (bf16)v.y; q.h[2] = (bf16)v.z; q.h[3] = (bf16)v.w;
    ((unsigned long long*)(RAW + (size_t)row * ldraw))[tid] = q.u;
  }
}

// ---------------- transpose+convert: M fp32 [8192][1024] -> MT bf16 [1024][8192] ----------
__global__ __launch_bounds__(256)
void transpose_cvt_kernel(const float* __restrict__ Msrc, bf16* __restrict__ MT)
{
  __shared__ float t[64][65];
  const int r0 = blockIdx.y << 6;
  const int c0 = blockIdx.x << 6;
  const int tid = threadIdx.x;
  const int lr = tid >> 4;
  const int lc = (tid & 15) << 2;
#pragma unroll
  for (int rr = 0; rr < 64; rr += 16) {
    const float4 v = *(const float4*)(Msrc + (size_t)(r0 + rr + lr) * 1024 + c0 + lc);
    t[rr + lr][lc] = v.x; t[rr + lr][lc + 1] = v.y;
    t[rr + lr][lc + 2] = v.z; t[rr + lr][lc + 3] = v.w;
  }
  __syncthreads();
#pragma unroll
  for (int cc = 0; cc < 64; cc += 16) {
    const int oc = cc + lr;
    union { bf16 h[4]; unsigned long long u; } p;
    p.h[0] = (bf16)t[lc][oc];     p.h[1] = (bf16)t[lc + 1][oc];
    p.h[2] = (bf16)t[lc + 2][oc]; p.h[3] = (bf16)t[lc + 3][oc];
    *(unsigned long long*)(MT + (size_t)(c0 + oc) * 8192 + r0 + lc) = p.u;
  }
}

// ---------------- elementwise fp32 -> bf16 ----------------
__global__ void cvt_bf16_kernel(const float* __restrict__ src, bf16* __restrict__ dst, int n4) {
  const int i = blockIdx.x * blockDim.x + threadIdx.x;
  if (i >= n4) return;
  const float4 v = ((const float4*)src)[i];
  union { bf16 h[4]; unsigned long long u; } p;
  p.h[0] = (bf16)v.x; p.h[1] = (bf16)v.y; p.h[2] = (bf16)v.z; p.h[3] = (bf16)v.w;
  ((unsigned long long*)dst)[i] = p.u;
}

// W2 [1000][4096] fp32 -> [1024][4096] bf16, rows >= 1000 zeroed
__global__ void cvt_w2_kernel(const float* __restrict__ src, bf16* __restrict__ dst) {
  const int i = blockIdx.x * blockDim.x + threadIdx.x;   // vec4 index
  const int row = i >> 10;                               // 1024 vec4 per row
  union { bf16 h[4]; unsigned long long u; } p;
  if (row < 1000) {
    const float4 v = ((const float4*)src)[i];
    p.h[0] = (bf16)v.x; p.h[1] = (bf16)v.y; p.h[2] = (bf16)v.z; p.h[3] = (bf16)v.w;
  } else {
    p.u = 0ull;
  }
  ((unsigned long long*)dst)[i] = p.u;
}

// ---------------- sparsemax over rows of S (fp16, m=8192) -> CW bf16 ----------------
// tau = root of f(tau) = sum relu(z - tau) - 1 (translation-invariant: z = cos).
// Newton from tau0 = (sum - 1)/m: monotone, exact on piecewise-linear f.
__global__ __launch_bounds__(256)
void sparsemax_kernel(const _Float16* __restrict__ S, bf16* __restrict__ CW)
{
  const int row = blockIdx.x;
  const int tid = threadIdx.x;
  const f16x8* zs = (const f16x8*)(S + (size_t)row * 8192);
  float z[32];
  float lsum = 0.f;
#pragma unroll
  for (int t = 0; t < 4; ++t) {
    const f16x8 v = zs[t * 256 + tid];
#pragma unroll
    for (int j = 0; j < 8; ++j) { const float f = (float)v[j]; z[t * 8 + j] = f; lsum += f; }
  }
  __shared__ float redS[4], redC[4];
  float s = lsum;
#pragma unroll
  for (int o = 32; o > 0; o >>= 1) s += __shfl_down(s, o);
  if ((tid & 63) == 0) redS[tid >> 6] = s;
  __syncthreads();
  float tau = (redS[0] + redS[1] + redS[2] + redS[3] - 1.0f) * (1.0f / 8192.0f);

  for (int it = 0; it < 64; ++it) {
    float ls = 0.f, lc = 0.f;
#pragma unroll
    for (int j = 0; j < 32; ++j) {
      const float v = z[j];
      if (v > tau) { ls += v; lc += 1.0f; }
    }
#pragma unroll
    for (int o = 32; o > 0; o >>= 1) { ls += __shfl_down(ls, o); lc += __shfl_down(lc, o); }
    __syncthreads();                       // protect redS/redC from previous iteration's reads
    if ((tid & 63) == 0) { redS[tid >> 6] = ls; redC[tid >> 6] = lc; }
    __syncthreads();
    const float Ssum = redS[0] + redS[1] + redS[2] + redS[3];
    const float Csum = redC[0] + redC[1] + redC[2] + redC[3];
    const float ntau = (Ssum - 1.0f) / Csum;
    if (!(ntau > tau)) break;              // uniform: computed from shared values
    tau = ntau;
  }

  typedef __bf16 obf8 __attribute__((ext_vector_type(8)));
  obf8* out = (obf8*)(CW + (size_t)row * 8192);
#pragma unroll
  for (int t = 0; t < 4; ++t) {
    obf8 o;
#pragma unroll
    for (int j = 0; j < 8; ++j) {
      const float w = z[t * 8 + j] - tau;
      o[j] = (bf16)(w > 0.f ? w : 0.f);
    }
    out[t * 256 + tid] = o;
  }
}

// ---------------- launch ----------------
extern "C" void kernel_launch(void* const* d_in, const int* in_sizes, int n_in,
                              void* d_out, int out_size, void* d_ws, size_t ws_size,
                              hipStream_t stream)
{
  const float* enc = (const float*)d_in[0];   // [4096,1024]
  const float* mem = (const float*)d_in[1];   // [8192,1024]
  // d_in[2] = loss_weights, unused by reference
  const float* W1  = (const float*)d_in[3];   // [4096,2048]
  const float* b1  = (const float*)d_in[4];   // [4096]
  const float* W2  = (const float*)d_in[5];   // [1000,4096]
  const float* b2  = (const float*)d_in[6];   // [1000]
  float* out = (float*)d_out;                 // [4096,1000]
  char* ws = (char*)d_ws;

  _Float16* S = (_Float16*)(ws + WS_OFF_S);
  bf16* CW  = (bf16*)(ws + WS_OFF_CW);
  bf16* MT  = (bf16*)(ws + WS_OFF_MT);
  bf16* W1B = (bf16*)(ws + WS_OFF_W1B);
  bf16* W2B = (bf16*)(ws + WS_OFF_W2B);
  bf16* FI  = (bf16*)(ws + WS_OFF_FI);
  bf16* XN  = (bf16*)(ws + WS_OFF_XN);
  bf16* YN  = (bf16*)(ws + WS_OFF_YN);
  bf16* H   = (bf16*)(ws + WS_OFF_H);

  // conversions / normalization
  rownorm_kernel<<<4096, 256, 0, stream>>>(enc, XN, FI, 2048);       // also fills FI[:, :1024]
  rownorm_kernel<<<8192, 256, 0, stream>>>(mem, YN, (bf16*)nullptr, 0);
  transpose_cvt_kernel<<<dim3(16, 128), 256, 0, stream>>>(mem, MT);
  cvt_bf16_kernel<<<8192, 256, 0, stream>>>(W1, W1B, 2097152);
  cvt_w2_kernel<<<4096, 256, 0, stream>>>(W2, W2B);

  // S = Xn @ Yn^T (cosine similarities), fp16
  gemm_nt<0><<<dim3(64, 32), 256, 0, stream>>>(XN, YN, S, nullptr, 1024, 8192, 0, 0);
  // CW = sparsemax rows
  sparsemax_kernel<<<4096, 256, 0, stream>>>(S, CW);
  // FI[:, 1024:] = CW @ M  (via MT = M^T, NT form)
  gemm_nt<1><<<dim3(8, 32), 256, 0, stream>>>(CW, MT, FI, nullptr, 8192, 2048, 0, 1024);
  // H = relu(FI @ W1^T + b1)
  gemm_nt<2><<<dim3(32, 32), 256, 0, stream>>>(FI, W1B, H, b1, 2048, 4096, 0, 0);
  // out = H @ W2^T + b2 (N padded to 1024, store cols < 1000)
  gemm_nt<3><<<dim3(8, 32), 256, 0, stream>>>(H, W2B, out, b2, 4096, 1000, 1000, 0);
}

// Round 3
// 505.862 us; speedup vs baseline: 1.2437x; 1.2437x over previous
//
#include <hip/hip_runtime.h>

typedef __bf16 bf16;
typedef __bf16 bf16x4 __attribute__((ext_vector_type(4)));
typedef __bf16 bf16x8 __attribute__((ext_vector_type(8)));
typedef float f32x4 __attribute__((ext_vector_type(4)));
typedef _Float16 f16x8 __attribute__((ext_vector_type(8)));

// ---------------- workspace layout (bytes) ----------------
// S     fp16 [4096][8192]  67,108,864  @ 0           (reused for H bf16 [4096][4096])
// PAIRS u32  [4096][4096]  67,108,864  @ 67,108,864  (per row: slots 0..4094 = (f16 w)<<16 | idx,
//                                                     slot 4095 = count)
// MB    bf16 [8192][1024]  16,777,216  @ 134,217,728 (raw bf16 copy of memory_set)
// W1B   bf16 [4096][2048]  16,777,216  @ 150,994,944
// W2B   bf16 [1024][4096]   8,388,608  @ 167,772,160 (rows 1000..1023 zero-padded)
// FI    bf16 [4096][2048]  16,777,216  @ 176,160,768 (cols 0..1023 enc, 1024..2047 memvec)
// XN    bf16 [4096][1024]   8,388,608  @ 192,937,984
// YN    bf16 [8192][1024]  16,777,216  @ 201,326,592
// total 218,103,808 (identical to proven round-2 footprint)
#define WS_OFF_S    (0ull)
#define WS_OFF_PAIR (67108864ull)
#define WS_OFF_MB   (134217728ull)
#define WS_OFF_W1B  (150994944ull)
#define WS_OFF_W2B  (167772160ull)
#define WS_OFF_FI   (176160768ull)
#define WS_OFF_XN   (192937984ull)
#define WS_OFF_YN   (201326592ull)
#define WS_OFF_H    (0ull)
#define K_MAX 4095

__device__ __forceinline__ void gload_lds16(const void* g, void* l) {
  __builtin_amdgcn_global_load_lds(
      (const __attribute__((address_space(1))) void*)g,
      (__attribute__((address_space(3))) void*)l, 16, 0, 0);
}

// ---------------- NT bf16 GEMM: C = A[M,K] * B[N,K]^T ----------------
// 128x128 tile, BK=64, 256 threads (4 waves 2x2), mfma_f32_16x16x32_bf16.
// Staging: per wave, 4 x global_load_lds dwordx4 per tile-half (each issue =
// 64 lanes x 16 B = 1024 B = 8 rows). Linear LDS dest; global source col is
// inverse-swizzled (byte ^= ((row&7)<<4)); ds_read_b128 applies the same XOR
// -> 2-way bank conflict (free).  LDS[row][c] = G[row][c ^ ((row&7)<<4)].
// EPI: 0 = fp16 store (scores) | 2 = +bias, ReLU, bf16
//      3 = +bias, fp32, col<colLimit predicate
template<int EPI>
__global__ __launch_bounds__(256)
void gemm_nt(const bf16* __restrict__ A, const bf16* __restrict__ B,
             void* __restrict__ Cout, const float* __restrict__ bias,
             int K, int ldc, int colLimit)
{
  __shared__ alignas(16) bf16 As[128 * 64];
  __shared__ alignas(16) bf16 Bs[128 * 64];
  const int tid  = threadIdx.x;
  const int lane = tid & 63;
  const int wave = tid >> 6;
  const int wr = wave >> 1, wc = wave & 1;
  const int bm0 = blockIdx.y << 7;
  const int bn0 = blockIdx.x << 7;

  // staging: wave w owns tile rows [32w, 32w+32); issue i covers 8 rows (1024 B)
  const int lr   = lane >> 3;                    // 0..7: row within 8-row group
  const int lcb  = (lane & 7) << 4;              // byte col 0..112
  const int scolb = lcb ^ (lr << 4);             // inverse-swizzled source col
  const int row0 = (wave << 5) + lr;
  const char* Ag = (const char*)(A + (size_t)(bm0 + row0) * K) + scolb;
  const char* Bg = (const char*)(B + (size_t)(bn0 + row0) * K) + scolb;
  char* Al = (char*)As + (wave << 12);
  char* Bl = (char*)Bs + (wave << 12);
  const size_t rstride8 = (size_t)16 * K;        // 8 rows * K * 2 bytes

  // precomputed swizzled ds_read byte offsets (constant across K loop)
  int offA[2][4], offB[2][4];
  const int kb = (lane >> 4) << 4;               // lane's 16B k-slot
#pragma unroll
  for (int m = 0; m < 4; ++m) {
    const int rA = (wr << 6) + (m << 4) + (lane & 15);
    const int rB = (wc << 6) + (m << 4) + (lane & 15);
#pragma unroll
    for (int ks = 0; ks < 2; ++ks) {
      offA[ks][m] = (rA << 7) + ((((ks << 6) + kb)) ^ ((rA & 7) << 4));
      offB[ks][m] = (rB << 7) + ((((ks << 6) + kb)) ^ ((rB & 7) << 4));
    }
  }

  f32x4 acc[4][4];
#pragma unroll
  for (int m = 0; m < 4; ++m)
#pragma unroll
    for (int n = 0; n < 4; ++n) acc[m][n] = (f32x4)(0.0f);

  const char* Asb = (const char*)As;
  const char* Bsb = (const char*)Bs;
  const int nk = K >> 6;
  for (int kt = 0; kt < nk; ++kt) {
#pragma unroll
    for (int i = 0; i < 4; ++i) gload_lds16(Ag + i * rstride8, Al + (i << 10));
#pragma unroll
    for (int i = 0; i < 4; ++i) gload_lds16(Bg + i * rstride8, Bl + (i << 10));
    Ag += 128; Bg += 128;                        // BK*2 bytes
    __syncthreads();                             // drains vmcnt -> LDS ready
#pragma unroll
    for (int ks = 0; ks < 2; ++ks) {
      bf16x8 av[4], bv[4];
#pragma unroll
      for (int m = 0; m < 4; ++m) av[m] = *(const bf16x8*)(Asb + offA[ks][m]);
#pragma unroll
      for (int n = 0; n < 4; ++n) bv[n] = *(const bf16x8*)(Bsb + offB[ks][n]);
#pragma unroll
      for (int m = 0; m < 4; ++m)
#pragma unroll
        for (int n = 0; n < 4; ++n)
          acc[m][n] = __builtin_amdgcn_mfma_f32_16x16x32_bf16(av[m], bv[n], acc[m][n], 0, 0, 0);
    }
    __syncthreads();                             // before next stage overwrites
  }

  // epilogue: C/D layout col = lane&15, row = (lane>>4)*4 + j  [m89/m91 verified]
  const int r0 = bm0 + (wr << 6) + ((lane >> 4) << 2);
  const int c0 = bn0 + (wc << 6) + (lane & 15);
#pragma unroll
  for (int m = 0; m < 4; ++m) {
#pragma unroll
    for (int n = 0; n < 4; ++n) {
      const int col = c0 + (n << 4);
#pragma unroll
      for (int j = 0; j < 4; ++j) {
        const int row = r0 + (m << 4) + j;
        const float v = acc[m][n][j];
        if (EPI == 0) {
          ((_Float16*)Cout)[(size_t)row * ldc + col] = (_Float16)v;
        } else if (EPI == 2) {
          float t = v + bias[col];
          t = t > 0.f ? t : 0.f;
          ((bf16*)Cout)[(size_t)row * ldc + col] = (bf16)t;
        } else {
          if (col < colLimit)
            ((float*)Cout)[(size_t)row * ldc + col] = v + bias[col];
        }
      }
    }
  }
}

// ---------------- row-normalize fp32 -> bf16 (and optional raw bf16 copy) ----------------
__global__ __launch_bounds__(256)
void rownorm_kernel(const float* __restrict__ X, bf16* __restrict__ XN,
                    bf16* __restrict__ RAW, int ldraw)
{
  const int row = blockIdx.x;
  const int tid = threadIdx.x;
  const float4 v = ((const float4*)(X + (size_t)row * 1024))[tid];
  float ss = v.x * v.x + v.y * v.y + v.z * v.z + v.w * v.w;
#pragma unroll
  for (int o = 32; o > 0; o >>= 1) ss += __shfl_down(ss, o);
  __shared__ float red[4];
  if ((tid & 63) == 0) red[tid >> 6] = ss;
  __syncthreads();
  const float rn = rsqrtf(red[0] + red[1] + red[2] + red[3] + 1e-6f);
  union { bf16 h[4]; unsigned long long u; } p;
  p.h[0] = (bf16)(v.x * rn); p.h[1] = (bf16)(v.y * rn);
  p.h[2] = (bf16)(v.z * rn); p.h[3] = (bf16)(v.w * rn);
  ((unsigned long long*)(XN + (size_t)row * 1024))[tid] = p.u;
  if (RAW != nullptr) {
    union { bf16 h[4]; unsigned long long u; } q;
    q.h[0] = (bf16)v.x; q.h[1] = (bf16)v.y; q.h[2] = (bf16)v.z; q.h[3] = (bf16)v.w;
    ((unsigned long long*)(RAW + (size_t)row * ldraw))[tid] = q.u;
  }
}

// ---------------- elementwise fp32 -> bf16 ----------------
__global__ void cvt_bf16_kernel(const float* __restrict__ src, bf16* __restrict__ dst, int n4) {
  const int i = blockIdx.x * blockDim.x + threadIdx.x;
  if (i >= n4) return;
  const float4 v = ((const float4*)src)[i];
  union { bf16 h[4]; unsigned long long u; } p;
  p.h[0] = (bf16)v.x; p.h[1] = (bf16)v.y; p.h[2] = (bf16)v.z; p.h[3] = (bf16)v.w;
  ((unsigned long long*)dst)[i] = p.u;
}

// W2 [1000][4096] fp32 -> [1024][4096] bf16, rows >= 1000 zeroed
__global__ void cvt_w2_kernel(const float* __restrict__ src, bf16* __restrict__ dst) {
  const int i = blockIdx.x * blockDim.x + threadIdx.x;   // vec4 index
  const int row = i >> 10;                               // 1024 vec4 per row
  union { bf16 h[4]; unsigned long long u; } p;
  if (row < 1000) {
    const float4 v = ((const float4*)src)[i];
    p.h[0] = (bf16)v.x; p.h[1] = (bf16)v.y; p.h[2] = (bf16)v.z; p.h[3] = (bf16)v.w;
  } else {
    p.u = 0ull;
  }
  ((unsigned long long*)dst)[i] = p.u;
}

// ---------------- sparsemax over rows of S (fp16, m=8192) -> compact (idx,w) list -------
// tau = root of f(tau) = sum relu(z - tau) - 1. Newton from tau0 = (sum-1)/m:
// monotone and exact on piecewise-linear f. Support for this data ~90/8192, so
// emit a compacted list: PAIRS[row][slot] = (f16(w) << 16) | idx, count in slot 4095.
__global__ __launch_bounds__(256)
void sparsemax_compact_kernel(const _Float16* __restrict__ S, unsigned* __restrict__ PAIRS)
{
  const int row = blockIdx.x;
  const int tid = threadIdx.x;
  const f16x8* zs = (const f16x8*)(S + (size_t)row * 8192);
  float z[32];
  float lsum = 0.f;
#pragma unroll
  for (int t = 0; t < 4; ++t) {
    const f16x8 v = zs[t * 256 + tid];
#pragma unroll
    for (int j = 0; j < 8; ++j) { const float f = (float)v[j]; z[t * 8 + j] = f; lsum += f; }
  }
  __shared__ float redS[4], redC[4];
  __shared__ int lcnt;
  if (tid == 0) lcnt = 0;
  float s = lsum;
#pragma unroll
  for (int o = 32; o > 0; o >>= 1) s += __shfl_down(s, o);
  if ((tid & 63) == 0) redS[tid >> 6] = s;
  __syncthreads();
  float tau = (redS[0] + redS[1] + redS[2] + redS[3] - 1.0f) * (1.0f / 8192.0f);

  for (int it = 0; it < 64; ++it) {
    float ls = 0.f, lc = 0.f;
#pragma unroll
    for (int j = 0; j < 32; ++j) {
      const float v = z[j];
      if (v > tau) { ls += v; lc += 1.0f; }
    }
#pragma unroll
    for (int o = 32; o > 0; o >>= 1) { ls += __shfl_down(ls, o); lc += __shfl_down(lc, o); }
    __syncthreads();                       // protect redS/redC from previous iteration's reads
    if ((tid & 63) == 0) { redS[tid >> 6] = ls; redC[tid >> 6] = lc; }
    __syncthreads();
    const float Ssum = redS[0] + redS[1] + redS[2] + redS[3];
    const float Csum = redC[0] + redC[1] + redC[2] + redC[3];
    const float ntau = (Ssum - 1.0f) / Csum;
    if (!(ntau > tau)) break;              // uniform decision: from shared values
    tau = ntau;
  }

  // compact support into PAIRS[row]
  unsigned* pr = PAIRS + ((size_t)row << 12);
#pragma unroll
  for (int t = 0; t < 4; ++t) {
#pragma unroll
    for (int j = 0; j < 8; ++j) {
      const float w = z[t * 8 + j] - tau;
      if (w > 0.f) {
        const int slot = atomicAdd(&lcnt, 1);
        if (slot < K_MAX) {
          union { _Float16 h; unsigned short us; } cv; cv.h = (_Float16)w;
          const unsigned idx = (unsigned)((t * 256 + tid) * 8 + j);
          pr[slot] = ((unsigned)cv.us << 16) | idx;
        }
      }
    }
  }
  __syncthreads();
  if (tid == 0) pr[K_MAX] = (unsigned)min(lcnt, K_MAX);
}

// ---------------- sparse gather: FI[:,1024:] = sum_i w_i * MB[idx_i] ----------------
// one block per row; 256 threads x 4 dims; (idx,w) broadcast via LDS chunks.
__global__ __launch_bounds__(256)
void gather_memvec_kernel(const unsigned* __restrict__ PAIRS, const bf16* __restrict__ MB,
                          bf16* __restrict__ FI)
{
  const int row = blockIdx.x;
  const int tid = threadIdx.x;
  const unsigned* pr = PAIRS + ((size_t)row << 12);
  const int cnt = (int)pr[K_MAX];
  __shared__ unsigned pbuf[256];
  float4 acc = make_float4(0.f, 0.f, 0.f, 0.f);
  for (int base = 0; base < cnt; base += 256) {
    const int nb = min(256, cnt - base);
    __syncthreads();
    if (tid < nb) pbuf[tid] = pr[base + tid];
    __syncthreads();
    for (int e = 0; e < nb; ++e) {
      const unsigned pk = pbuf[e];
      union { unsigned short us; _Float16 h; } cv; cv.us = (unsigned short)(pk >> 16);
      const float w = (float)cv.h;
      const size_t idx = (size_t)(pk & 0xffffu);
      const bf16x4 v = ((const bf16x4*)(MB + (idx << 10)))[tid];
      acc.x += w * (float)v[0];
      acc.y += w * (float)v[1];
      acc.z += w * (float)v[2];
      acc.w += w * (float)v[3];
    }
  }
  union { bf16 h[4]; unsigned long long u; } p;
  p.h[0] = (bf16)acc.x; p.h[1] = (bf16)acc.y; p.h[2] = (bf16)acc.z; p.h[3] = (bf16)acc.w;
  ((unsigned long long*)(FI + (size_t)row * 2048 + 1024))[tid] = p.u;
}

// ---------------- launch ----------------
extern "C" void kernel_launch(void* const* d_in, const int* in_sizes, int n_in,
                              void* d_out, int out_size, void* d_ws, size_t ws_size,
                              hipStream_t stream)
{
  const float* enc = (const float*)d_in[0];   // [4096,1024]
  const float* mem = (const float*)d_in[1];   // [8192,1024]
  // d_in[2] = loss_weights, unused by reference
  const float* W1  = (const float*)d_in[3];   // [4096,2048]
  const float* b1  = (const float*)d_in[4];   // [4096]
  const float* W2  = (const float*)d_in[5];   // [1000,4096]
  const float* b2  = (const float*)d_in[6];   // [1000]
  float* out = (float*)d_out;                 // [4096,1000]
  char* ws = (char*)d_ws;

  _Float16* S = (_Float16*)(ws + WS_OFF_S);
  unsigned* PAIRS = (unsigned*)(ws + WS_OFF_PAIR);
  bf16* MB  = (bf16*)(ws + WS_OFF_MB);
  bf16* W1B = (bf16*)(ws + WS_OFF_W1B);
  bf16* W2B = (bf16*)(ws + WS_OFF_W2B);
  bf16* FI  = (bf16*)(ws + WS_OFF_FI);
  bf16* XN  = (bf16*)(ws + WS_OFF_XN);
  bf16* YN  = (bf16*)(ws + WS_OFF_YN);
  bf16* H   = (bf16*)(ws + WS_OFF_H);

  // conversions / normalization (RAW paths fill FI[:, :1024] and MB)
  rownorm_kernel<<<4096, 256, 0, stream>>>(enc, XN, FI, 2048);
  rownorm_kernel<<<8192, 256, 0, stream>>>(mem, YN, MB, 1024);
  cvt_bf16_kernel<<<8192, 256, 0, stream>>>(W1, W1B, 2097152);
  cvt_w2_kernel<<<4096, 256, 0, stream>>>(W2, W2B);

  // S = Xn @ Yn^T (cosine similarities), fp16
  gemm_nt<0><<<dim3(64, 32), 256, 0, stream>>>(XN, YN, S, nullptr, 1024, 8192, 0);
  // compact sparsemax
  sparsemax_compact_kernel<<<4096, 256, 0, stream>>>(S, PAIRS);
  // FI[:, 1024:] = sparse CW @ M
  gather_memvec_kernel<<<4096, 256, 0, stream>>>(PAIRS, MB, FI);
  // H = relu(FI @ W1^T + b1)
  gemm_nt<2><<<dim3(32, 32), 256, 0, stream>>>(FI, W1B, H, b1, 2048, 4096, 0);
  // out = H @ W2^T + b2 (N padded to 1024, store cols < 1000)
  gemm_nt<3><<<dim3(8, 32), 256, 0, stream>>>(H, W2B, out, b2, 4096, 1000, 1000);
}

// Round 4
// 468.365 us; speedup vs baseline: 1.3433x; 1.0801x over previous
//
#include <hip/hip_runtime.h>

typedef __bf16 bf16;
typedef __bf16 bf16x4 __attribute__((ext_vector_type(4)));
typedef __bf16 bf16x8 __attribute__((ext_vector_type(8)));
typedef float f32x4 __attribute__((ext_vector_type(4)));
typedef _Float16 f16x8 __attribute__((ext_vector_type(8)));

// ---------------- workspace layout (bytes) ----------------
// S    fp16 [4096][8192]    67,108,864  @ 0           (reused for H bf16 [4096][4096])
// P4   fp32 [4][4096][1024] 67,108,864  @ 67,108,864  (MLP2 split-K partials)
// MB   bf16 [8192][1024]    16,777,216  @ 134,217,728 (raw bf16 copy of memory_set)
// W1B  bf16 [4096][2048]    16,777,216  @ 150,994,944
// W2B  bf16 [1024][4096]     8,388,608  @ 167,772,160 (rows 1000..1023 zero-padded)
// FI   bf16 [4096][2048]    16,777,216  @ 176,160,768 (cols 0..1023 enc, 1024..2047 memvec)
// XN   bf16 [4096][1024]     8,388,608  @ 192,937,984
// YN   bf16 [8192][1024]    16,777,216  @ 201,326,592
// total 218,103,808 (identical to proven round-2/3 footprint)
#define WS_OFF_S    (0ull)
#define WS_OFF_P4   (67108864ull)
#define WS_OFF_MB   (134217728ull)
#define WS_OFF_W1B  (150994944ull)
#define WS_OFF_W2B  (167772160ull)
#define WS_OFF_FI   (176160768ull)
#define WS_OFF_XN   (192937984ull)
#define WS_OFF_YN   (201326592ull)
#define WS_OFF_H    (0ull)

__device__ __forceinline__ void gload_lds16(const void* g, void* l) {
  __builtin_amdgcn_global_load_lds(
      (const __attribute__((address_space(1))) void*)g,
      (__attribute__((address_space(3))) void*)l, 16, 0, 0);
}

// ---------------- NT bf16 GEMM: C = A[M,*] * B[N,*]^T over K columns ----------------
// 128x128 tile, BK=64, 256 threads (4 waves 2x2), mfma_f32_16x16x32_bf16.
// ldab = element row stride of A and B; K = loop extent; blockIdx.z selects a
// K-chunk at column offset z*K (split-K; partials per z for EPI=4).
// Staging: per wave, 4 x global_load_lds dwordx4 per tile-half (each issue =
// 64 lanes x 16 B = 1024 B = 8 rows). Linear LDS dest; global source col is
// inverse-swizzled (byte ^= ((row&7)<<4)); ds_read_b128 applies the same XOR
// -> 2-way bank conflict (free).  LDS[row][c] = G[row][c ^ ((row&7)<<4)].
// EPI: 0 = fp16 store (scores) | 2 = +bias, ReLU, bf16 | 4 = fp32 partial store
template<int EPI>
__global__ __launch_bounds__(256)
void gemm_nt(const bf16* __restrict__ A, const bf16* __restrict__ B,
             void* __restrict__ Cout, const float* __restrict__ bias,
             int K, int ldab, int ldc)
{
  __shared__ alignas(16) bf16 As[128 * 64];
  __shared__ alignas(16) bf16 Bs[128 * 64];
  const int tid  = threadIdx.x;
  const int lane = tid & 63;
  const int wave = tid >> 6;
  const int wr = wave >> 1, wc = wave & 1;
  const int bm0 = blockIdx.y << 7;
  const int bn0 = blockIdx.x << 7;
  const int zc  = blockIdx.z;                    // K-chunk (0 unless split-K)

  // staging: wave w owns tile rows [32w, 32w+32); issue i covers 8 rows (1024 B)
  const int lr   = lane >> 3;                    // 0..7: row within 8-row group
  const int lcb  = (lane & 7) << 4;              // byte col 0..112
  const int scolb = lcb ^ (lr << 4);             // inverse-swizzled source col
  const int row0 = (wave << 5) + lr;
  const char* Ag = (const char*)(A + (size_t)(bm0 + row0) * ldab + (size_t)zc * K) + scolb;
  const char* Bg = (const char*)(B + (size_t)(bn0 + row0) * ldab + (size_t)zc * K) + scolb;
  char* Al = (char*)As + (wave << 12);
  char* Bl = (char*)Bs + (wave << 12);
  const size_t rstride8 = (size_t)16 * ldab;     // 8 rows * ldab * 2 bytes

  // precomputed swizzled ds_read byte offsets (constant across K loop)
  int offA[2][4], offB[2][4];
  const int kb = (lane >> 4) << 4;               // lane's 16B k-slot
#pragma unroll
  for (int m = 0; m < 4; ++m) {
    const int rA = (wr << 6) + (m << 4) + (lane & 15);
    const int rB = (wc << 6) + (m << 4) + (lane & 15);
#pragma unroll
    for (int ks = 0; ks < 2; ++ks) {
      offA[ks][m] = (rA << 7) + ((((ks << 6) + kb)) ^ ((rA & 7) << 4));
      offB[ks][m] = (rB << 7) + ((((ks << 6) + kb)) ^ ((rB & 7) << 4));
    }
  }

  f32x4 acc[4][4];
#pragma unroll
  for (int m = 0; m < 4; ++m)
#pragma unroll
    for (int n = 0; n < 4; ++n) acc[m][n] = (f32x4)(0.0f);

  const char* Asb = (const char*)As;
  const char* Bsb = (const char*)Bs;
  const int nk = K >> 6;
  for (int kt = 0; kt < nk; ++kt) {
#pragma unroll
    for (int i = 0; i < 4; ++i) gload_lds16(Ag + i * rstride8, Al + (i << 10));
#pragma unroll
    for (int i = 0; i < 4; ++i) gload_lds16(Bg + i * rstride8, Bl + (i << 10));
    Ag += 128; Bg += 128;                        // BK*2 bytes
    __syncthreads();                             // drains vmcnt -> LDS ready
#pragma unroll
    for (int ks = 0; ks < 2; ++ks) {
      bf16x8 av[4], bv[4];
#pragma unroll
      for (int m = 0; m < 4; ++m) av[m] = *(const bf16x8*)(Asb + offA[ks][m]);
#pragma unroll
      for (int n = 0; n < 4; ++n) bv[n] = *(const bf16x8*)(Bsb + offB[ks][n]);
#pragma unroll
      for (int m = 0; m < 4; ++m)
#pragma unroll
        for (int n = 0; n < 4; ++n)
          acc[m][n] = __builtin_amdgcn_mfma_f32_16x16x32_bf16(av[m], bv[n], acc[m][n], 0, 0, 0);
    }
    __syncthreads();                             // before next stage overwrites
  }

  // epilogue: C/D layout col = lane&15, row = (lane>>4)*4 + j  [m89/m91 verified]
  const int r0 = bm0 + (wr << 6) + ((lane >> 4) << 2);
  const int c0 = bn0 + (wc << 6) + (lane & 15);
#pragma unroll
  for (int m = 0; m < 4; ++m) {
#pragma unroll
    for (int n = 0; n < 4; ++n) {
      const int col = c0 + (n << 4);
#pragma unroll
      for (int j = 0; j < 4; ++j) {
        const int row = r0 + (m << 4) + j;
        const float v = acc[m][n][j];
        if (EPI == 0) {
          ((_Float16*)Cout)[(size_t)row * ldc + col] = (_Float16)v;
        } else if (EPI == 2) {
          float t = v + bias[col];
          t = t > 0.f ? t : 0.f;
          ((bf16*)Cout)[(size_t)row * ldc + col] = (bf16)t;
        } else {
          ((float*)Cout)[((size_t)zc << 22) + (size_t)row * ldc + col] = v;
        }
      }
    }
  }
}

// ---------------- split-K reduce + bias: out[row][c<1000] = sum_z P4[z][row][c] + b2[c] ----
__global__ __launch_bounds__(256)
void reduce_bias_kernel(const float* __restrict__ P4, const float* __restrict__ b2,
                        float* __restrict__ out)
{
  const int row = blockIdx.x;
  const int t = threadIdx.x;
  if (t >= 250) return;                          // 250 * 4 = 1000 cols
  const size_t base = (size_t)row * 1024 + (t << 2);
  const float4 p0 = *(const float4*)(P4 + base);
  const float4 p1 = *(const float4*)(P4 + base + (1ull << 22));
  const float4 p2 = *(const float4*)(P4 + base + (2ull << 22));
  const float4 p3 = *(const float4*)(P4 + base + (3ull << 22));
  const float4 bb = ((const float4*)b2)[t];
  float4 r;
  r.x = p0.x + p1.x + p2.x + p3.x + bb.x;
  r.y = p0.y + p1.y + p2.y + p3.y + bb.y;
  r.z = p0.z + p1.z + p2.z + p3.z + bb.z;
  r.w = p0.w + p1.w + p2.w + p3.w + bb.w;
  *(float4*)(out + (size_t)row * 1000 + (t << 2)) = r;   // 1000*4B = 16B-aligned rows
}

// ---------------- row-normalize fp32 -> bf16 (and optional raw bf16 copy) ----------------
__global__ __launch_bounds__(256)
void rownorm_kernel(const float* __restrict__ X, bf16* __restrict__ XN,
                    bf16* __restrict__ RAW, int ldraw)
{
  const int row = blockIdx.x;
  const int tid = threadIdx.x;
  const float4 v = ((const float4*)(X + (size_t)row * 1024))[tid];
  float ss = v.x * v.x + v.y * v.y + v.z * v.z + v.w * v.w;
#pragma unroll
  for (int o = 32; o > 0; o >>= 1) ss += __shfl_down(ss, o);
  __shared__ float red[4];
  if ((tid & 63) == 0) red[tid >> 6] = ss;
  __syncthreads();
  const float rn = rsqrtf(red[0] + red[1] + red[2] + red[3] + 1e-6f);
  union { bf16 h[4]; unsigned long long u; } p;
  p.h[0] = (bf16)(v.x * rn); p.h[1] = (bf16)(v.y * rn);
  p.h[2] = (bf16)(v.z * rn); p.h[3] = (bf16)(v.w * rn);
  ((unsigned long long*)(XN + (size_t)row * 1024))[tid] = p.u;
  if (RAW != nullptr) {
    union { bf16 h[4]; unsigned long long u; } q;
    q.h[0] = (bf16)v.x; q.h[1] = (bf16)v.y; q.h[2] = (bf16)v.z; q.h[3] = (bf16)v.w;
    ((unsigned long long*)(RAW + (size_t)row * ldraw))[tid] = q.u;
  }
}

// ---------------- elementwise fp32 -> bf16 ----------------
__global__ void cvt_bf16_kernel(const float* __restrict__ src, bf16* __restrict__ dst, int n4) {
  const int i = blockIdx.x * blockDim.x + threadIdx.x;
  if (i >= n4) return;
  const float4 v = ((const float4*)src)[i];
  union { bf16 h[4]; unsigned long long u; } p;
  p.h[0] = (bf16)v.x; p.h[1] = (bf16)v.y; p.h[2] = (bf16)v.z; p.h[3] = (bf16)v.w;
  ((unsigned long long*)dst)[i] = p.u;
}

// W2 [1000][4096] fp32 -> [1024][4096] bf16, rows >= 1000 zeroed
__global__ void cvt_w2_kernel(const float* __restrict__ src, bf16* __restrict__ dst) {
  const int i = blockIdx.x * blockDim.x + threadIdx.x;   // vec4 index
  const int row = i >> 10;                               // 1024 vec4 per row
  union { bf16 h[4]; unsigned long long u; } p;
  if (row < 1000) {
    const float4 v = ((const float4*)src)[i];
    p.h[0] = (bf16)v.x; p.h[1] = (bf16)v.y; p.h[2] = (bf16)v.z; p.h[3] = (bf16)v.w;
  } else {
    p.u = 0ull;
  }
  ((unsigned long long*)dst)[i] = p.u;
}

// ---------------- fused sparsemax + gather ----------------
// Per row: tau = root of f(tau) = sum relu(z - tau) - 1 (Newton from (sum-1)/m,
// monotone & exact on piecewise-linear f). Support (~90/8192 for this data) is
// compacted into an LDS list (chunked rounds; overflow-safe re-push), then
// FI[row, 1024:] = sum_i w_i * MB[idx_i] accumulated directly. No global PAIRS.
#define LCAP 1024
__global__ __launch_bounds__(256)
void sparsemax_gather_kernel(const _Float16* __restrict__ S, const bf16* __restrict__ MB,
                             bf16* __restrict__ FI)
{
  const int row = blockIdx.x;
  const int tid = threadIdx.x;
  const f16x8* zs = (const f16x8*)(S + (size_t)row * 8192);
  float z[32];
  float lsum = 0.f;
#pragma unroll
  for (int t = 0; t < 4; ++t) {
    const f16x8 v = zs[t * 256 + tid];
#pragma unroll
    for (int j = 0; j < 8; ++j) { const float f = (float)v[j]; z[t * 8 + j] = f; lsum += f; }
  }
  __shared__ float redS[4], redC[4];
  __shared__ unsigned pbuf[LCAP];
  __shared__ int lcnt;
  float s = lsum;
#pragma unroll
  for (int o = 32; o > 0; o >>= 1) s += __shfl_down(s, o);
  if ((tid & 63) == 0) redS[tid >> 6] = s;
  __syncthreads();
  float tau = (redS[0] + redS[1] + redS[2] + redS[3] - 1.0f) * (1.0f / 8192.0f);

  for (int it = 0; it < 64; ++it) {
    float ls = 0.f, lc = 0.f;
#pragma unroll
    for (int j = 0; j < 32; ++j) {
      const float v = z[j];
      if (v > tau) { ls += v; lc += 1.0f; }
    }
#pragma unroll
    for (int o = 32; o > 0; o >>= 1) { ls += __shfl_down(ls, o); lc += __shfl_down(lc, o); }
    __syncthreads();                       // protect redS/redC from previous iteration's reads
    if ((tid & 63) == 0) { redS[tid >> 6] = ls; redC[tid >> 6] = lc; }
    __syncthreads();
    const float Ssum = redS[0] + redS[1] + redS[2] + redS[3];
    const float Csum = redC[0] + redC[1] + redC[2] + redC[3];
    const float ntau = (Ssum - 1.0f) / Csum;
    if (!(ntau > tau)) break;              // uniform decision: from shared values
    tau = ntau;
  }

  // support bitmask per thread
  unsigned pend = 0;
#pragma unroll
  for (int j = 0; j < 32; ++j)
    if (z[j] > tau) pend |= (1u << j);

  float4 acc = make_float4(0.f, 0.f, 0.f, 0.f);
  for (;;) {
    if (tid == 0) lcnt = 0;
    __syncthreads();
    // push pending entries (f16 w | u16 idx); keep overflow for next round
    unsigned rem = pend;
    while (rem) {
      const int j = __ffs(rem) - 1;
      rem &= rem - 1;
      const int slot = atomicAdd(&lcnt, 1);
      if (slot < LCAP) {
        union { _Float16 h; unsigned short us; } cv; cv.h = (_Float16)(z[j] - tau);
        const unsigned idx = (unsigned)(((j >> 3) * 256 + tid) * 8 + (j & 7));
        pbuf[slot] = ((unsigned)cv.us << 16) | idx;
        pend &= ~(1u << j);
      }
    }
    __syncthreads();
    const int nb = min(lcnt, LCAP);
    for (int e = 0; e < nb; ++e) {
      const unsigned pk = pbuf[e];
      union { unsigned short us; _Float16 h; } cv; cv.us = (unsigned short)(pk >> 16);
      const float w = (float)cv.h;
      const size_t idx = (size_t)(pk & 0xffffu);
      const bf16x4 v = ((const bf16x4*)(MB + (idx << 10)))[tid];
      acc.x += w * (float)v[0];
      acc.y += w * (float)v[1];
      acc.z += w * (float)v[2];
      acc.w += w * (float)v[3];
    }
    if (!__syncthreads_or(pend != 0)) break;   // also fences pbuf reads vs next push
  }

  union { bf16 h[4]; unsigned long long u; } p;
  p.h[0] = (bf16)acc.x; p.h[1] = (bf16)acc.y; p.h[2] = (bf16)acc.z; p.h[3] = (bf16)acc.w;
  ((unsigned long long*)(FI + (size_t)row * 2048 + 1024))[tid] = p.u;
}

// ---------------- launch ----------------
extern "C" void kernel_launch(void* const* d_in, const int* in_sizes, int n_in,
                              void* d_out, int out_size, void* d_ws, size_t ws_size,
                              hipStream_t stream)
{
  const float* enc = (const float*)d_in[0];   // [4096,1024]
  const float* mem = (const float*)d_in[1];   // [8192,1024]
  // d_in[2] = loss_weights, unused by reference
  const float* W1  = (const float*)d_in[3];   // [4096,2048]
  const float* b1  = (const float*)d_in[4];   // [4096]
  const float* W2  = (const float*)d_in[5];   // [1000,4096]
  const float* b2  = (const float*)d_in[6];   // [1000]
  float* out = (float*)d_out;                 // [4096,1000]
  char* ws = (char*)d_ws;

  _Float16* S = (_Float16*)(ws + WS_OFF_S);
  float* P4 = (float*)(ws + WS_OFF_P4);
  bf16* MB  = (bf16*)(ws + WS_OFF_MB);
  bf16* W1B = (bf16*)(ws + WS_OFF_W1B);
  bf16* W2B = (bf16*)(ws + WS_OFF_W2B);
  bf16* FI  = (bf16*)(ws + WS_OFF_FI);
  bf16* XN  = (bf16*)(ws + WS_OFF_XN);
  bf16* YN  = (bf16*)(ws + WS_OFF_YN);
  bf16* H   = (bf16*)(ws + WS_OFF_H);

  // conversions / normalization (RAW paths fill FI[:, :1024] and MB)
  rownorm_kernel<<<4096, 256, 0, stream>>>(enc, XN, FI, 2048);
  rownorm_kernel<<<8192, 256, 0, stream>>>(mem, YN, MB, 1024);
  cvt_bf16_kernel<<<8192, 256, 0, stream>>>(W1, W1B, 2097152);
  cvt_w2_kernel<<<4096, 256, 0, stream>>>(W2, W2B);

  // S = Xn @ Yn^T (cosine similarities), fp16
  gemm_nt<0><<<dim3(64, 32), 256, 0, stream>>>(XN, YN, S, nullptr, 1024, 1024, 8192);
  // fused sparsemax + sparse gather -> FI[:, 1024:]
  sparsemax_gather_kernel<<<4096, 256, 0, stream>>>(S, MB, FI);
  // H = relu(FI @ W1^T + b1)   (H overwrites S region; S dead after gather)
  gemm_nt<2><<<dim3(32, 32), 256, 0, stream>>>(FI, W1B, H, b1, 2048, 2048, 4096);
  // MLP2 split-K=4: P4[z] = H[:, z*1024:(z+1)*1024] @ W2B[:, z*1024:(z+1)*1024]^T
  gemm_nt<4><<<dim3(8, 32, 4), 256, 0, stream>>>(H, W2B, P4, nullptr, 1024, 4096, 1024);
  // out = sum_z P4[z] + b2 (cols < 1000)
  reduce_bias_kernel<<<4096, 256, 0, stream>>>(P4, b2, out);
}

// Round 6
// 449.650 us; speedup vs baseline: 1.3992x; 1.0416x over previous
//
#include <hip/hip_runtime.h>

typedef __bf16 bf16;
typedef __bf16 bf16x4 __attribute__((ext_vector_type(4)));
typedef __bf16 bf16x8 __attribute__((ext_vector_type(8)));
typedef float f32x4 __attribute__((ext_vector_type(4)));
typedef _Float16 f16x8 __attribute__((ext_vector_type(8)));

// ---------------- workspace layout (bytes) ----------------
// S    fp16 [4096][8192]    67,108,864  @ 0           (reused for H bf16 [4096][4096])
// P4   fp32 [4][4096][1024] 67,108,864  @ 67,108,864  (MLP2 split-K partials)
// MB   bf16 [8192][1024]    16,777,216  @ 134,217,728 (raw bf16 copy of memory_set)
// W1B  bf16 [4096][2048]    16,777,216  @ 150,994,944
// W2B  bf16 [1024][4096]     8,388,608  @ 167,772,160 (rows 1000..1023 zero-padded)
// FI   bf16 [4096][2048]    16,777,216  @ 176,160,768 (cols 0..1023 enc, 1024..2047 memvec)
// XN   bf16 [4096][1024]     8,388,608  @ 192,937,984
// YN   bf16 [8192][1024]    16,777,216  @ 201,326,592
// total 218,103,808
#define WS_OFF_S    (0ull)
#define WS_OFF_P4   (67108864ull)
#define WS_OFF_MB   (134217728ull)
#define WS_OFF_W1B  (150994944ull)
#define WS_OFF_W2B  (167772160ull)
#define WS_OFF_FI   (176160768ull)
#define WS_OFF_XN   (192937984ull)
#define WS_OFF_YN   (201326592ull)
#define WS_OFF_H    (0ull)

__device__ __forceinline__ void gload_lds16(const void* g, void* l) {
  __builtin_amdgcn_global_load_lds(
      (const __attribute__((address_space(1))) void*)g,
      (__attribute__((address_space(3))) void*)l, 16, 0, 0);
}

// ---------------- NT bf16 GEMM, 256x256 tile, counted-vmcnt pipeline ----------------
// C = A[M,*] * B[N,*]^T. BK=64, 512 threads = 8 waves (2 Mrow x 4 Ncol), per-wave
// output 128x64 (acc[8][4] f32x4). LDS: 2 bufs x (A 32KB + B 32KB) = 128 KiB.
// Pipeline (T3/T4): depth-1 prefetch; stage(t+1) is in flight DURING compute(t);
// main-loop wait is s_waitcnt vmcnt(8) (never 0 until the last tile). Race safety:
// stage(t+2)->buf[cur] is issued only after the post-compute barrier of tile t, and
// its first reader is behind the vmcnt+barrier at head of iter t+2.
// Staging per wave: rows [32w,32w+32) of A and of B, 4 issues each of 8 rows
// (64 lanes x 16B, linear LDS dest), global source col pre-swizzled so that
// LDS[r][c] = G[r][c ^ ((r&7)<<4)]; ds_read_b128 applies the same XOR (2-way, free).
// EPI: 0 = fp16 store (scores) | 2 = +bias, ReLU, bf16 | 4 = fp32 partial store (split-K z)
template<int EPI>
__global__ __launch_bounds__(512, 2)
void gemm_nt256(const bf16* __restrict__ A, const bf16* __restrict__ B,
                void* __restrict__ Cout, const float* __restrict__ bias,
                int K, int ldab, int ldc)
{
  __shared__ alignas(16) bf16 As[2][256 * 64];
  __shared__ alignas(16) bf16 Bs[2][256 * 64];
  const int tid  = threadIdx.x;
  const int lane = tid & 63;
  const int wave = tid >> 6;                     // 0..7
  const int wr = wave >> 2, wc = wave & 3;       // 2 x 4
  const int bm0 = blockIdx.y << 8;
  const int bn0 = blockIdx.x << 8;
  const int zc  = blockIdx.z;                    // K-chunk (0 unless split-K)

  // staging: wave w owns rows [32w, 32w+32) of both tiles; issue i = 8 rows = 1024 B
  const int lr    = lane >> 3;                   // row within 8-row group
  const int scolb = ((lane & 7) << 4) ^ (lr << 4);
  const int row0  = (wave << 5) + lr;
  const char* Ag = (const char*)(A + (size_t)(bm0 + row0) * ldab + (size_t)zc * K) + scolb;
  const char* Bg = (const char*)(B + (size_t)(bn0 + row0) * ldab + (size_t)zc * K) + scolb;
  char* Alds = (char*)As + (wave << 12);         // + buf*32768 + i*1024
  char* Blds = (char*)Bs + (wave << 12);
  const size_t rstride8 = (size_t)16 * ldab;     // 8 rows in bytes

  // swizzled ds_read byte offsets (constant across K loop)
  int offA[2][8], offB[2][4];
  const int kb = (lane >> 4) << 4;               // lane's 16B k-slot
#pragma unroll
  for (int ks = 0; ks < 2; ++ks) {
#pragma unroll
    for (int m = 0; m < 8; ++m) {
      const int rA = (wr << 7) + (m << 4) + (lane & 15);
      offA[ks][m] = (rA << 7) + ((((ks << 6) + kb)) ^ ((rA & 7) << 4));
    }
#pragma unroll
    for (int n = 0; n < 4; ++n) {
      const int rB = (wc << 6) + (n << 4) + (lane & 15);
      offB[ks][n] = (rB << 7) + ((((ks << 6) + kb)) ^ ((rB & 7) << 4));
    }
  }

  f32x4 acc[8][4];
#pragma unroll
  for (int m = 0; m < 8; ++m)
#pragma unroll
    for (int n = 0; n < 4; ++n) acc[m][n] = (f32x4)(0.0f);

  auto STAGE = [&](int buf) {
    char* Ad = Alds + (buf << 15);
    char* Bd = Blds + (buf << 15);
#pragma unroll
    for (int i = 0; i < 4; ++i) gload_lds16(Ag + i * rstride8, Ad + (i << 10));
#pragma unroll
    for (int i = 0; i < 4; ++i) gload_lds16(Bg + i * rstride8, Bd + (i << 10));
    Ag += 128; Bg += 128;                        // advance one K-tile (BK*2 bytes)
  };

  const int nt = K >> 6;                         // requires nt >= 2 (all call sites: 16/32)
  STAGE(0);
  STAGE(1);
  int cur = 0;
  for (int t = 0; t < nt; ++t) {
    if (t + 1 < nt) { asm volatile("s_waitcnt vmcnt(8)" ::: "memory"); }
    else            { asm volatile("s_waitcnt vmcnt(0)" ::: "memory"); }
    __builtin_amdgcn_s_barrier();
    asm volatile("" ::: "memory");
    const char* Ab = (const char*)As + (cur << 15);
    const char* Bb = (const char*)Bs + (cur << 15);
    __builtin_amdgcn_s_setprio(1);
#pragma unroll
    for (int ks = 0; ks < 2; ++ks) {
      bf16x8 av[8], bv[4];
#pragma unroll
      for (int m = 0; m < 8; ++m) av[m] = *(const bf16x8*)(Ab + offA[ks][m]);
#pragma unroll
      for (int n = 0; n < 4; ++n) bv[n] = *(const bf16x8*)(Bb + offB[ks][n]);
#pragma unroll
      for (int m = 0; m < 8; ++m)
#pragma unroll
        for (int n = 0; n < 4; ++n)
          acc[m][n] = __builtin_amdgcn_mfma_f32_16x16x32_bf16(av[m], bv[n], acc[m][n], 0, 0, 0);
    }
    __builtin_amdgcn_s_setprio(0);
    asm volatile("" ::: "memory");
    __builtin_amdgcn_s_barrier();                // all waves done reading buf[cur]
    if (t + 2 < nt) STAGE(cur);                  // overwrite buf[cur] with tile t+2
    cur ^= 1;
  }

  // epilogue: C/D layout col = lane&15, row = (lane>>4)*4 + j  [m89/m91 verified]
  const int r0 = bm0 + (wr << 7) + ((lane >> 4) << 2);
  const int c0 = bn0 + (wc << 6) + (lane & 15);
#pragma unroll
  for (int m = 0; m < 8; ++m) {
#pragma unroll
    for (int n = 0; n < 4; ++n) {
      const int col = c0 + (n << 4);
#pragma unroll
      for (int j = 0; j < 4; ++j) {
        const int row = r0 + (m << 4) + j;
        const float v = acc[m][n][j];
        if (EPI == 0) {
          ((_Float16*)Cout)[(size_t)row * ldc + col] = (_Float16)v;
        } else if (EPI == 2) {
          float t2 = v + bias[col];
          t2 = t2 > 0.f ? t2 : 0.f;
          ((bf16*)Cout)[(size_t)row * ldc + col] = (bf16)t2;
        } else {
          ((float*)Cout)[((size_t)zc << 22) + (size_t)row * ldc + col] = v;
        }
      }
    }
  }
}

// ---------------- split-K reduce + bias: out[row][c<1000] = sum_z P4[z][row][c] + b2[c] ----
__global__ __launch_bounds__(256)
void reduce_bias_kernel(const float* __restrict__ P4, const float* __restrict__ b2,
                        float* __restrict__ out)
{
  const int row = blockIdx.x;
  const int t = threadIdx.x;
  if (t >= 250) return;                          // 250 * 4 = 1000 cols
  const size_t base = (size_t)row * 1024 + (t << 2);
  const float4 p0 = *(const float4*)(P4 + base);
  const float4 p1 = *(const float4*)(P4 + base + (1ull << 22));
  const float4 p2 = *(const float4*)(P4 + base + (2ull << 22));
  const float4 p3 = *(const float4*)(P4 + base + (3ull << 22));
  const float4 bb = ((const float4*)b2)[t];
  float4 r;
  r.x = p0.x + p1.x + p2.x + p3.x + bb.x;
  r.y = p0.y + p1.y + p2.y + p3.y + bb.y;
  r.z = p0.z + p1.z + p2.z + p3.z + bb.z;
  r.w = p0.w + p1.w + p2.w + p3.w + bb.w;
  *(float4*)(out + (size_t)row * 1000 + (t << 2)) = r;
}

// ---------------- row-normalize fp32 -> bf16 (and optional raw bf16 copy) ----------------
__global__ __launch_bounds__(256)
void rownorm_kernel(const float* __restrict__ X, bf16* __restrict__ XN,
                    bf16* __restrict__ RAW, int ldraw)
{
  const int row = blockIdx.x;
  const int tid = threadIdx.x;
  const float4 v = ((const float4*)(X + (size_t)row * 1024))[tid];
  float ss = v.x * v.x + v.y * v.y + v.z * v.z + v.w * v.w;
#pragma unroll
  for (int o = 32; o > 0; o >>= 1) ss += __shfl_down(ss, o);
  __shared__ float red[4];
  if ((tid & 63) == 0) red[tid >> 6] = ss;
  __syncthreads();
  const float rn = rsqrtf(red[0] + red[1] + red[2] + red[3] + 1e-6f);
  union { bf16 h[4]; unsigned long long u; } p;
  p.h[0] = (bf16)(v.x * rn); p.h[1] = (bf16)(v.y * rn);
  p.h[2] = (bf16)(v.z * rn); p.h[3] = (bf16)(v.w * rn);
  ((unsigned long long*)(XN + (size_t)row * 1024))[tid] = p.u;
  if (RAW != nullptr) {
    union { bf16 h[4]; unsigned long long u; } q;
    q.h[0] = (bf16)v.x; q.h[1] = (bf16)v.y; q.h[2] = (bf16)v.z; q.h[3] = (bf16)v.w;
    ((unsigned long long*)(RAW + (size_t)row * ldraw))[tid] = q.u;
  }
}

// ---------------- elementwise fp32 -> bf16 ----------------
__global__ void cvt_bf16_kernel(const float* __restrict__ src, bf16* __restrict__ dst, int n4) {
  const int i = blockIdx.x * blockDim.x + threadIdx.x;
  if (i >= n4) return;
  const float4 v = ((const float4*)src)[i];
  union { bf16 h[4]; unsigned long long u; } p;
  p.h[0] = (bf16)v.x; p.h[1] = (bf16)v.y; p.h[2] = (bf16)v.z; p.h[3] = (bf16)v.w;
  ((unsigned long long*)dst)[i] = p.u;
}

// W2 [1000][4096] fp32 -> [1024][4096] bf16, rows >= 1000 zeroed
__global__ void cvt_w2_kernel(const float* __restrict__ src, bf16* __restrict__ dst) {
  const int i = blockIdx.x * blockDim.x + threadIdx.x;   // vec4 index
  const int row = i >> 10;                               // 1024 vec4 per row
  union { bf16 h[4]; unsigned long long u; } p;
  if (row < 1000) {
    const float4 v = ((const float4*)src)[i];
    p.h[0] = (bf16)v.x; p.h[1] = (bf16)v.y; p.h[2] = (bf16)v.z; p.h[3] = (bf16)v.w;
  } else {
    p.u = 0ull;
  }
  ((unsigned long long*)dst)[i] = p.u;
}

// ---------------- fused sparsemax + gather (unchanged, proven) ----------------
#define LCAP 1024
__global__ __launch_bounds__(256)
void sparsemax_gather_kernel(const _Float16* __restrict__ S, const bf16* __restrict__ MB,
                             bf16* __restrict__ FI)
{
  const int row = blockIdx.x;
  const int tid = threadIdx.x;
  const f16x8* zs = (const f16x8*)(S + (size_t)row * 8192);
  float z[32];
  float lsum = 0.f;
#pragma unroll
  for (int t = 0; t < 4; ++t) {
    const f16x8 v = zs[t * 256 + tid];
#pragma unroll
    for (int j = 0; j < 8; ++j) { const float f = (float)v[j]; z[t * 8 + j] = f; lsum += f; }
  }
  __shared__ float redS[4], redC[4];
  __shared__ unsigned pbuf[LCAP];
  __shared__ int lcnt;
  float s = lsum;
#pragma unroll
  for (int o = 32; o > 0; o >>= 1) s += __shfl_down(s, o);
  if ((tid & 63) == 0) redS[tid >> 6] = s;
  __syncthreads();
  float tau = (redS[0] + redS[1] + redS[2] + redS[3] - 1.0f) * (1.0f / 8192.0f);

  for (int it = 0; it < 64; ++it) {
    float ls = 0.f, lc = 0.f;
#pragma unroll
    for (int j = 0; j < 32; ++j) {
      const float v = z[j];
      if (v > tau) { ls += v; lc += 1.0f; }
    }
#pragma unroll
    for (int o = 32; o > 0; o >>= 1) { ls += __shfl_down(ls, o); lc += __shfl_down(lc, o); }
    __syncthreads();
    if ((tid & 63) == 0) { redS[tid >> 6] = ls; redC[tid >> 6] = lc; }
    __syncthreads();
    const float Ssum = redS[0] + redS[1] + redS[2] + redS[3];
    const float Csum = redC[0] + redC[1] + redC[2] + redC[3];
    const float ntau = (Ssum - 1.0f) / Csum;
    if (!(ntau > tau)) break;
    tau = ntau;
  }

  unsigned pend = 0;
#pragma unroll
  for (int j = 0; j < 32; ++j)
    if (z[j] > tau) pend |= (1u << j);

  float4 acc = make_float4(0.f, 0.f, 0.f, 0.f);
  for (;;) {
    if (tid == 0) lcnt = 0;
    __syncthreads();
    unsigned rem = pend;
    while (rem) {
      const int j = __ffs(rem) - 1;
      rem &= rem - 1;
      const int slot = atomicAdd(&lcnt, 1);
      if (slot < LCAP) {
        union { _Float16 h; unsigned short us; } cv; cv.h = (_Float16)(z[j] - tau);
        const unsigned idx = (unsigned)(((j >> 3) * 256 + tid) * 8 + (j & 7));
        pbuf[slot] = ((unsigned)cv.us << 16) | idx;
        pend &= ~(1u << j);
      }
    }
    __syncthreads();
    const int nb = min(lcnt, LCAP);
    for (int e = 0; e < nb; ++e) {
      const unsigned pk = pbuf[e];
      union { unsigned short us; _Float16 h; } cv; cv.us = (unsigned short)(pk >> 16);
      const float w = (float)cv.h;
      const size_t idx = (size_t)(pk & 0xffffu);
      const bf16x4 v = ((const bf16x4*)(MB + (idx << 10)))[tid];
      acc.x += w * (float)v[0];
      acc.y += w * (float)v[1];
      acc.z += w * (float)v[2];
      acc.w += w * (float)v[3];
    }
    if (!__syncthreads_or(pend != 0)) break;
  }

  union { bf16 h[4]; unsigned long long u; } p;
  p.h[0] = (bf16)acc.x; p.h[1] = (bf16)acc.y; p.h[2] = (bf16)acc.z; p.h[3] = (bf16)acc.w;
  ((unsigned long long*)(FI + (size_t)row * 2048 + 1024))[tid] = p.u;
}

// ---------------- launch ----------------
extern "C" void kernel_launch(void* const* d_in, const int* in_sizes, int n_in,
                              void* d_out, int out_size, void* d_ws, size_t ws_size,
                              hipStream_t stream)
{
  const float* enc = (const float*)d_in[0];   // [4096,1024]
  const float* mem = (const float*)d_in[1];   // [8192,1024]
  // d_in[2] = loss_weights, unused by reference
  const float* W1  = (const float*)d_in[3];   // [4096,2048]
  const float* b1  = (const float*)d_in[4];   // [4096]
  const float* W2  = (const float*)d_in[5];   // [1000,4096]
  const float* b2  = (const float*)d_in[6];   // [1000]
  float* out = (float*)d_out;                 // [4096,1000]
  char* ws = (char*)d_ws;

  _Float16* S = (_Float16*)(ws + WS_OFF_S);
  float* P4 = (float*)(ws + WS_OFF_P4);
  bf16* MB  = (bf16*)(ws + WS_OFF_MB);
  bf16* W1B = (bf16*)(ws + WS_OFF_W1B);
  bf16* W2B = (bf16*)(ws + WS_OFF_W2B);
  bf16* FI  = (bf16*)(ws + WS_OFF_FI);
  bf16* XN  = (bf16*)(ws + WS_OFF_XN);
  bf16* YN  = (bf16*)(ws + WS_OFF_YN);
  bf16* H   = (bf16*)(ws + WS_OFF_H);

  // conversions / normalization (RAW paths fill FI[:, :1024] and MB)
  rownorm_kernel<<<4096, 256, 0, stream>>>(enc, XN, FI, 2048);
  rownorm_kernel<<<8192, 256, 0, stream>>>(mem, YN, MB, 1024);
  cvt_bf16_kernel<<<8192, 256, 0, stream>>>(W1, W1B, 2097152);
  cvt_w2_kernel<<<4096, 256, 0, stream>>>(W2, W2B);

  // S = Xn @ Yn^T (cosine similarities), fp16
  gemm_nt256<0><<<dim3(32, 16), 512, 0, stream>>>(XN, YN, S, nullptr, 1024, 1024, 8192);
  // fused sparsemax + sparse gather -> FI[:, 1024:]
  sparsemax_gather_kernel<<<4096, 256, 0, stream>>>(S, MB, FI);
  // H = relu(FI @ W1^T + b1)   (H overwrites S region; S dead after gather)
  gemm_nt256<2><<<dim3(16, 16), 512, 0, stream>>>(FI, W1B, H, b1, 2048, 2048, 4096);
  // MLP2 split-K=4: P4[z] = H[:, z*1024:(z+1)*1024] @ W2B[:, z*1024:(z+1)*1024]^T
  gemm_nt256<4><<<dim3(4, 16, 4), 512, 0, stream>>>(H, W2B, P4, nullptr, 1024, 4096, 1024);
  // out = sum_z P4[z] + b2 (cols < 1000)
  reduce_bias_kernel<<<4096, 256, 0, stream>>>(P4, b2, out);
}

// Round 7
// 446.982 us; speedup vs baseline: 1.4075x; 1.0060x over previous
//
#include <hip/hip_runtime.h>

typedef __bf16 bf16;
typedef __bf16 bf16x4 __attribute__((ext_vector_type(4)));
typedef __bf16 bf16x8 __attribute__((ext_vector_type(8)));
typedef float f32x4 __attribute__((ext_vector_type(4)));
typedef _Float16 f16x8 __attribute__((ext_vector_type(8)));
typedef unsigned short ushort4v __attribute__((ext_vector_type(4)));

// ---------------- workspace layout (bytes) ----------------
// S    fp16 [4096][8192]    67,108,864  @ 0           (reused for H bf16 [4096][4096])
// P4   fp32 [4][4096][1024] 67,108,864  @ 67,108,864  (MLP2 split-K partials)
// MB   bf16 [8192][1024]    16,777,216  @ 134,217,728 (raw bf16 copy of memory_set)
// W1B  bf16 [4096][2048]    16,777,216  @ 150,994,944
// W2B  bf16 [1024][4096]     8,388,608  @ 167,772,160 (rows 1000..1023 zero-padded)
// FI   bf16 [4096][2048]    16,777,216  @ 176,160,768 (cols 0..1023 enc, 1024..2047 memvec)
// XN   bf16 [4096][1024]     8,388,608  @ 192,937,984
// YN   bf16 [8192][1024]    16,777,216  @ 201,326,592
// total 218,103,808
#define WS_OFF_S    (0ull)
#define WS_OFF_P4   (67108864ull)
#define WS_OFF_MB   (134217728ull)
#define WS_OFF_W1B  (150994944ull)
#define WS_OFF_W2B  (167772160ull)
#define WS_OFF_FI   (176160768ull)
#define WS_OFF_XN   (192937984ull)
#define WS_OFF_YN   (201326592ull)
#define WS_OFF_H    (0ull)

__device__ __forceinline__ void gload_lds16(const void* g, void* l) {
  __builtin_amdgcn_global_load_lds(
      (const __attribute__((address_space(1))) void*)g,
      (__attribute__((address_space(3))) void*)l, 16, 0, 0);
}

__device__ __forceinline__ f32x4 bf4_to_f32(bf16x4 v) {
  const ushort4v u = __builtin_bit_cast(ushort4v, v);
  f32x4 r;
#pragma unroll
  for (int k = 0; k < 4; ++k) {
    const unsigned q = ((unsigned)u[k]) << 16;
    r[k] = __builtin_bit_cast(float, q);
  }
  return r;
}

__device__ __forceinline__ float f16bits_to_f32(unsigned hb) {
  return (float)__builtin_bit_cast(_Float16, (unsigned short)hb);
}

// ---------------- NT bf16 GEMM, 256x256 tile, counted-vmcnt pipeline ----------------
// C = A[M,*] * B[N,*]^T. BK=64, 512 threads = 8 waves (2 Mrow x 4 Ncol), per-wave
// output 128x64 (acc[8][4] f32x4). LDS: 2 bufs x (A 32KB + B 32KB) = 128 KiB.
// Pipeline (T3/T4): depth-1 prefetch; stage(t+1) in flight DURING compute(t);
// main-loop wait is s_waitcnt vmcnt(8), never 0 until the last tile.
// T1: XCD-chunked bijective blockIdx swizzle (all call sites have nwg % 8 == 0).
// Staging per wave: rows [32w,32w+32), 4 issues x 8 rows (64 lanes x 16B, linear LDS
// dest), global source col pre-swizzled: LDS[r][c] = G[r][c ^ ((r&7)<<4)];
// ds_read_b128 applies the same XOR (2-way conflict, free).
// EPI: 0 = fp16 store (scores) | 2 = +bias, ReLU, bf16 | 4 = fp32 partial store (split-K z)
template<int EPI>
__global__ __launch_bounds__(512, 2)
void gemm_nt256(const bf16* __restrict__ A, const bf16* __restrict__ B,
                void* __restrict__ Cout, const float* __restrict__ bias,
                int K, int ldab, int ldc)
{
  __shared__ alignas(16) bf16 As[2][256 * 64];
  __shared__ alignas(16) bf16 Bs[2][256 * 64];
  const int tid  = threadIdx.x;
  const int lane = tid & 63;
  const int wave = tid >> 6;                     // 0..7
  const int wr = wave >> 2, wc = wave & 3;       // 2 x 4
  // T1 XCD-chunked swizzle (bijective: nwg % 8 == 0 at all call sites)
  const int gx  = gridDim.x;
  const int nwg = gx * gridDim.y;
  int flat = blockIdx.y * gx + blockIdx.x;
  flat = (flat & 7) * (nwg >> 3) + (flat >> 3);
  const int bm0 = (flat / gx) << 8;
  const int bn0 = (flat % gx) << 8;
  const int zc  = blockIdx.z;                    // K-chunk (0 unless split-K)

  // staging: wave w owns rows [32w, 32w+32) of both tiles; issue i = 8 rows = 1024 B
  const int lr    = lane >> 3;                   // row within 8-row group
  const int scolb = ((lane & 7) << 4) ^ (lr << 4);
  const int row0  = (wave << 5) + lr;
  const char* Ag = (const char*)(A + (size_t)(bm0 + row0) * ldab + (size_t)zc * K) + scolb;
  const char* Bg = (const char*)(B + (size_t)(bn0 + row0) * ldab + (size_t)zc * K) + scolb;
  char* Alds = (char*)As + (wave << 12);         // + buf*32768 + i*1024
  char* Blds = (char*)Bs + (wave << 12);
  const size_t rstride8 = (size_t)16 * ldab;     // 8 rows in bytes

  // swizzled ds_read byte offsets (constant across K loop)
  int offA[2][8], offB[2][4];
  const int kb = (lane >> 4) << 4;               // lane's 16B k-slot
#pragma unroll
  for (int ks = 0; ks < 2; ++ks) {
#pragma unroll
    for (int m = 0; m < 8; ++m) {
      const int rA = (wr << 7) + (m << 4) + (lane & 15);
      offA[ks][m] = (rA << 7) + ((((ks << 6) + kb)) ^ ((rA & 7) << 4));
    }
#pragma unroll
    for (int n = 0; n < 4; ++n) {
      const int rB = (wc << 6) + (n << 4) + (lane & 15);
      offB[ks][n] = (rB << 7) + ((((ks << 6) + kb)) ^ ((rB & 7) << 4));
    }
  }

  f32x4 acc[8][4];
#pragma unroll
  for (int m = 0; m < 8; ++m)
#pragma unroll
    for (int n = 0; n < 4; ++n) acc[m][n] = (f32x4)(0.0f);

  auto STAGE = [&](int buf) {
    char* Ad = Alds + (buf << 15);
    char* Bd = Blds + (buf << 15);
#pragma unroll
    for (int i = 0; i < 4; ++i) gload_lds16(Ag + i * rstride8, Ad + (i << 10));
#pragma unroll
    for (int i = 0; i < 4; ++i) gload_lds16(Bg + i * rstride8, Bd + (i << 10));
    Ag += 128; Bg += 128;                        // advance one K-tile (BK*2 bytes)
  };

  const int nt = K >> 6;                         // requires nt >= 2 (all call sites: 16/32)
  STAGE(0);
  STAGE(1);
  int cur = 0;
  for (int t = 0; t < nt; ++t) {
    if (t + 1 < nt) { asm volatile("s_waitcnt vmcnt(8)" ::: "memory"); }
    else            { asm volatile("s_waitcnt vmcnt(0)" ::: "memory"); }
    __builtin_amdgcn_s_barrier();
    asm volatile("" ::: "memory");
    const char* Ab = (const char*)As + (cur << 15);
    const char* Bb = (const char*)Bs + (cur << 15);
    __builtin_amdgcn_s_setprio(1);
#pragma unroll
    for (int ks = 0; ks < 2; ++ks) {
      bf16x8 av[8], bv[4];
#pragma unroll
      for (int m = 0; m < 8; ++m) av[m] = *(const bf16x8*)(Ab + offA[ks][m]);
#pragma unroll
      for (int n = 0; n < 4; ++n) bv[n] = *(const bf16x8*)(Bb + offB[ks][n]);
#pragma unroll
      for (int m = 0; m < 8; ++m)
#pragma unroll
        for (int n = 0; n < 4; ++n)
          acc[m][n] = __builtin_amdgcn_mfma_f32_16x16x32_bf16(av[m], bv[n], acc[m][n], 0, 0, 0);
    }
    __builtin_amdgcn_s_setprio(0);
    asm volatile("" ::: "memory");
    __builtin_amdgcn_s_barrier();                // all waves done reading buf[cur]
    if (t + 2 < nt) STAGE(cur);                  // overwrite buf[cur] with tile t+2
    cur ^= 1;
  }

  // epilogue: C/D layout col = lane&15, row = (lane>>4)*4 + j  [m89/m91 verified]
  const int r0 = bm0 + (wr << 7) + ((lane >> 4) << 2);
  const int c0 = bn0 + (wc << 6) + (lane & 15);
#pragma unroll
  for (int m = 0; m < 8; ++m) {
#pragma unroll
    for (int n = 0; n < 4; ++n) {
      const int col = c0 + (n << 4);
#pragma unroll
      for (int j = 0; j < 4; ++j) {
        const int row = r0 + (m << 4) + j;
        const float v = acc[m][n][j];
        if (EPI == 0) {
          ((_Float16*)Cout)[(size_t)row * ldc + col] = (_Float16)v;
        } else if (EPI == 2) {
          float t2 = v + bias[col];
          t2 = t2 > 0.f ? t2 : 0.f;
          ((bf16*)Cout)[(size_t)row * ldc + col] = (bf16)t2;
        } else {
          ((float*)Cout)[((size_t)zc << 22) + (size_t)row * ldc + col] = v;
        }
      }
    }
  }
}

// ---------------- split-K reduce + bias: out[row][c<1000] = sum_z P4[z][row][c] + b2[c] ----
__global__ __launch_bounds__(256)
void reduce_bias_kernel(const float* __restrict__ P4, const float* __restrict__ b2,
                        float* __restrict__ out)
{
  const int row = blockIdx.x;
  const int t = threadIdx.x;
  if (t >= 250) return;                          // 250 * 4 = 1000 cols
  const size_t base = (size_t)row * 1024 + (t << 2);
  const float4 p0 = *(const float4*)(P4 + base);
  const float4 p1 = *(const float4*)(P4 + base + (1ull << 22));
  const float4 p2 = *(const float4*)(P4 + base + (2ull << 22));
  const float4 p3 = *(const float4*)(P4 + base + (3ull << 22));
  const float4 bb = ((const float4*)b2)[t];
  float4 r;
  r.x = p0.x + p1.x + p2.x + p3.x + bb.x;
  r.y = p0.y + p1.y + p2.y + p3.y + bb.y;
  r.z = p0.z + p1.z + p2.z + p3.z + bb.z;
  r.w = p0.w + p1.w + p2.w + p3.w + bb.w;
  *(float4*)(out + (size_t)row * 1000 + (t << 2)) = r;
}

// ---------------- row-normalize fp32 -> bf16 (and optional raw bf16 copy) ----------------
__global__ __launch_bounds__(256)
void rownorm_kernel(const float* __restrict__ X, bf16* __restrict__ XN,
                    bf16* __restrict__ RAW, int ldraw)
{
  const int row = blockIdx.x;
  const int tid = threadIdx.x;
  const float4 v = ((const float4*)(X + (size_t)row * 1024))[tid];
  float ss = v.x * v.x + v.y * v.y + v.z * v.z + v.w * v.w;
#pragma unroll
  for (int o = 32; o > 0; o >>= 1) ss += __shfl_down(ss, o);
  __shared__ float red[4];
  if ((tid & 63) == 0) red[tid >> 6] = ss;
  __syncthreads();
  const float rn = rsqrtf(red[0] + red[1] + red[2] + red[3] + 1e-6f);
  union { bf16 h[4]; unsigned long long u; } p;
  p.h[0] = (bf16)(v.x * rn); p.h[1] = (bf16)(v.y * rn);
  p.h[2] = (bf16)(v.z * rn); p.h[3] = (bf16)(v.w * rn);
  ((unsigned long long*)(XN + (size_t)row * 1024))[tid] = p.u;
  if (RAW != nullptr) {
    union { bf16 h[4]; unsigned long long u; } q;
    q.h[0] = (bf16)v.x; q.h[1] = (bf16)v.y; q.h[2] = (bf16)v.z; q.h[3] = (bf16)v.w;
    ((unsigned long long*)(RAW + (size_t)row * ldraw))[tid] = q.u;
  }
}

// ---------------- elementwise fp32 -> bf16 ----------------
__global__ void cvt_bf16_kernel(const float* __restrict__ src, bf16* __restrict__ dst, int n4) {
  const int i = blockIdx.x * blockDim.x + threadIdx.x;
  if (i >= n4) return;
  const float4 v = ((const float4*)src)[i];
  union { bf16 h[4]; unsigned long long u; } p;
  p.h[0] = (bf16)v.x; p.h[1] = (bf16)v.y; p.h[2] = (bf16)v.z; p.h[3] = (bf16)v.w;
  ((unsigned long long*)dst)[i] = p.u;
}

// W2 [1000][4096] fp32 -> [1024][4096] bf16, rows >= 1000 zeroed
__global__ void cvt_w2_kernel(const float* __restrict__ src, bf16* __restrict__ dst) {
  const int i = blockIdx.x * blockDim.x + threadIdx.x;   // vec4 index
  const int row = i >> 10;                               // 1024 vec4 per row
  union { bf16 h[4]; unsigned long long u; } p;
  if (row < 1000) {
    const float4 v = ((const float4*)src)[i];
    p.h[0] = (bf16)v.x; p.h[1] = (bf16)v.y; p.h[2] = (bf16)v.z; p.h[3] = (bf16)v.w;
  } else {
    p.u = 0ull;
  }
  ((unsigned long long*)dst)[i] = p.u;
}

// ---------------- fused sparsemax + gather (all-static z -> registers) ----------------
// tau = root of f(tau) = sum relu(z - tau) - 1; Newton from tau0 = (sum-1)/m is
// monotone & exact on piecewise-linear f. All z[] accesses use compile-time
// indices (rule #20: runtime-indexed arrays go to scratch -- round-6's VGPR=40
// proved z was spilled; this version keeps z in VGPRs). Support entries are
// compacted into LDS (chunked rounds, overflow-safe static re-push), then
// FI[row,1024:] = sum_i w_i * MB[idx_i] with a 2-unrolled vectorized gather.
#define LCAP 1024
__global__ __launch_bounds__(256)
void sparsemax_gather_kernel(const _Float16* __restrict__ S, const bf16* __restrict__ MB,
                             bf16* __restrict__ FI)
{
  const int row = blockIdx.x;
  const int tid = threadIdx.x;
  const f16x8* zs = (const f16x8*)(S + (size_t)row * 8192);
  float z[32];
  float lsum = 0.f;
#pragma unroll
  for (int t = 0; t < 4; ++t) {
    const f16x8 v = zs[t * 256 + tid];
#pragma unroll
    for (int j = 0; j < 8; ++j) { const float f = (float)v[j]; z[t * 8 + j] = f; lsum += f; }
  }
  __shared__ float redS[4], redC[4];
  __shared__ unsigned pbuf[LCAP];
  __shared__ int lcnt;
  float s = lsum;
#pragma unroll
  for (int o = 32; o > 0; o >>= 1) s += __shfl_down(s, o);
  if ((tid & 63) == 0) redS[tid >> 6] = s;
  __syncthreads();
  float tau = (redS[0] + redS[1] + redS[2] + redS[3] - 1.0f) * (1.0f / 8192.0f);

  for (int it = 0; it < 64; ++it) {
    float ls = 0.f, lc = 0.f;
#pragma unroll
    for (int j = 0; j < 32; ++j) {
      const float v = z[j];
      if (v > tau) { ls += v; lc += 1.0f; }
    }
#pragma unroll
    for (int o = 32; o > 0; o >>= 1) { ls += __shfl_down(ls, o); lc += __shfl_down(lc, o); }
    __syncthreads();
    if ((tid & 63) == 0) { redS[tid >> 6] = ls; redC[tid >> 6] = lc; }
    __syncthreads();
    const float Ssum = redS[0] + redS[1] + redS[2] + redS[3];
    const float Csum = redC[0] + redC[1] + redC[2] + redC[3];
    const float ntau = (Ssum - 1.0f) / Csum;
    if (!(ntau > tau)) break;              // uniform decision: from shared values
    tau = ntau;
  }

  // support bitmask per thread (static build)
  unsigned pend = 0;
#pragma unroll
  for (int b = 0; b < 32; ++b)
    if (z[b] > tau) pend |= (1u << b);

  const bf16* MBt = MB + (tid << 2);       // this thread's 4-dim slice base
  f32x4 acc0 = (f32x4)(0.0f), acc1 = (f32x4)(0.0f);
  for (;;) {
    if (tid == 0) lcnt = 0;
    __syncthreads();
    // static push: bit b <-> element ((b>>3)*256 + tid)*8 + (b&7)
#pragma unroll
    for (int b = 0; b < 32; ++b) {
      if (pend & (1u << b)) {
        const int slot = atomicAdd(&lcnt, 1);
        if (slot < LCAP) {
          const unsigned short wb =
              __builtin_bit_cast(unsigned short, (_Float16)(z[b] - tau));
          const unsigned idx = (unsigned)((((b >> 3) * 256 + tid) << 3) + (b & 7));
          pbuf[slot] = ((unsigned)wb << 16) | idx;
          pend &= ~(1u << b);
        }
      }
    }
    __syncthreads();
    const int nb = min(lcnt, LCAP);
    int e = 0;
    for (; e + 1 < nb; e += 2) {
      const uint2 pk2 = *(const uint2*)&pbuf[e];   // 8B LDS broadcast
      const float w0 = f16bits_to_f32(pk2.x >> 16);
      const float w1 = f16bits_to_f32(pk2.y >> 16);
      const bf16x4 v0 = *(const bf16x4*)(MBt + ((size_t)(pk2.x & 0xffffu) << 10));
      const bf16x4 v1 = *(const bf16x4*)(MBt + ((size_t)(pk2.y & 0xffffu) << 10));
      acc0 += bf4_to_f32(v0) * w0;
      acc1 += bf4_to_f32(v1) * w1;
    }
    if (e < nb) {
      const unsigned pk = pbuf[e];
      const float w = f16bits_to_f32(pk >> 16);
      const bf16x4 v = *(const bf16x4*)(MBt + ((size_t)(pk & 0xffffu) << 10));
      acc0 += bf4_to_f32(v) * w;
    }
    if (!__syncthreads_or(pend != 0)) break;   // also fences pbuf reads vs next push
  }

  const f32x4 acc = acc0 + acc1;
  union { bf16 h[4]; unsigned long long u; } p;
  p.h[0] = (bf16)acc[0]; p.h[1] = (bf16)acc[1];
  p.h[2] = (bf16)acc[2]; p.h[3] = (bf16)acc[3];
  ((unsigned long long*)(FI + (size_t)row * 2048 + 1024))[tid] = p.u;
}

// ---------------- launch ----------------
extern "C" void kernel_launch(void* const* d_in, const int* in_sizes, int n_in,
                              void* d_out, int out_size, void* d_ws, size_t ws_size,
                              hipStream_t stream)
{
  const float* enc = (const float*)d_in[0];   // [4096,1024]
  const float* mem = (const float*)d_in[1];   // [8192,1024]
  // d_in[2] = loss_weights, unused by reference
  const float* W1  = (const float*)d_in[3];   // [4096,2048]
  const float* b1  = (const float*)d_in[4];   // [4096]
  const float* W2  = (const float*)d_in[5];   // [1000,4096]
  const float* b2  = (const float*)d_in[6];   // [1000]
  float* out = (float*)d_out;                 // [4096,1000]
  char* ws = (char*)d_ws;

  _Float16* S = (_Float16*)(ws + WS_OFF_S);
  float* P4 = (float*)(ws + WS_OFF_P4);
  bf16* MB  = (bf16*)(ws + WS_OFF_MB);
  bf16* W1B = (bf16*)(ws + WS_OFF_W1B);
  bf16* W2B = (bf16*)(ws + WS_OFF_W2B);
  bf16* FI  = (bf16*)(ws + WS_OFF_FI);
  bf16* XN  = (bf16*)(ws + WS_OFF_XN);
  bf16* YN  = (bf16*)(ws + WS_OFF_YN);
  bf16* H   = (bf16*)(ws + WS_OFF_H);

  // conversions / normalization (RAW paths fill FI[:, :1024] and MB)
  rownorm_kernel<<<4096, 256, 0, stream>>>(enc, XN, FI, 2048);
  rownorm_kernel<<<8192, 256, 0, stream>>>(mem, YN, MB, 1024);
  cvt_bf16_kernel<<<8192, 256, 0, stream>>>(W1, W1B, 2097152);
  cvt_w2_kernel<<<4096, 256, 0, stream>>>(W2, W2B);

  // S = Xn @ Yn^T (cosine similarities), fp16
  gemm_nt256<0><<<dim3(32, 16), 512, 0, stream>>>(XN, YN, S, nullptr, 1024, 1024, 8192);
  // fused sparsemax + sparse gather -> FI[:, 1024:]
  sparsemax_gather_kernel<<<4096, 256, 0, stream>>>(S, MB, FI);
  // H = relu(FI @ W1^T + b1)   (H overwrites S region; S dead after gather)
  gemm_nt256<2><<<dim3(16, 16), 512, 0, stream>>>(FI, W1B, H, b1, 2048, 2048, 4096);
  // MLP2 split-K=4: P4[z] = H[:, z*1024:(z+1)*1024] @ W2B[:, z*1024:(z+1)*1024]^T
  gemm_nt256<4><<<dim3(4, 16, 4), 512, 0, stream>>>(H, W2B, P4, nullptr, 1024, 4096, 1024);
  // out = sum_z P4[z] + b2 (cols < 1000)
  reduce_bias_kernel<<<4096, 256, 0, stream>>>(P4, b2, out);
}